// Round 6
// baseline (332.257 us; speedup 1.0000x reference)
//
#include <hip/hip_runtime.h>
#include <hip/hip_bf16.h>

#define TT 2048
#define BB 8
#define DD 128
#define HH 4
#define BT (BB*TT)
#define BH (BB*HH)
#define SCALE 0.1767766952966369f

typedef __attribute__((ext_vector_type(8))) short short8;
typedef __attribute__((ext_vector_type(4))) short s16x4;
typedef __attribute__((ext_vector_type(4))) float f32x4;
typedef __hip_bfloat16 bf16;

#define MFMA16(a,b,c) __builtin_amdgcn_mfma_f32_16x16x32_bf16(a,b,c,0,0,0)

static __device__ inline short8 ldg8(const bf16* p) {
  return *reinterpret_cast<const short8*>(p);
}
static __device__ inline float b2f(bf16 x) { return __bfloat162float(x); }
static __device__ inline short f2bs(float x) {
  bf16 h = __float2bfloat16(x);
  return *reinterpret_cast<short*>(&h);
}
// load 8 contiguous f32 from global, convert to bf16 A/B-fragment
static __device__ inline short8 ldcvt8(const float* p) {
  f32x4 f0 = *reinterpret_cast<const f32x4*>(p);
  f32x4 f1 = *reinterpret_cast<const f32x4*>(p + 4);
  short8 r;
  #pragma unroll
  for (int i = 0; i < 4; ++i) { r[i] = f2bs(f0[i]); r[4+i] = f2bs(f1[i]); }
  return r;
}

// ---------------- Kernel 1: MFMA projections ----------------
// q is pre-scaled by 1/sqrt(head_dim) so attention kernels exp() directly.
__global__ __launch_bounds__(256) void proj_kernel(
    const float* __restrict__ lob, const float* __restrict__ hawkes,
    const float* __restrict__ Wp, const float* __restrict__ bp,
    const float* __restrict__ Win, const float* __restrict__ binp,
    bf16* __restrict__ qg, bf16* __restrict__ kg, bf16* __restrict__ vtg) {
  __shared__ bf16 hT[32*136];   // h tile [m][k], stride 136
  __shared__ bf16 vT[128*40];   // v^T tile [c][t], stride 40
  int tid = threadIdx.x;
  int wave = tid >> 6, lane = tid & 63;
  int lr = lane & 15, lq = lane >> 4;
  int r0 = blockIdx.x * 32;
  int b  = r0 >> 11, t0 = r0 & 2047;
  f32x4 z = {0.f,0.f,0.f,0.f};

  short8 alob[2][4], ahk[2];
  #pragma unroll
  for (int mt = 0; mt < 2; ++mt) {
    const float* lp = lob + (size_t)(r0 + mt*16 + lr)*128;
    #pragma unroll
    for (int kt = 0; kt < 4; ++kt) alob[mt][kt] = ldcvt8(lp + kt*32 + lq*8);
    ahk[mt] = ldcvt8(hawkes + (size_t)(r0 + mt*16 + lr)*32 + lq*8);
  }

  for (int nt = wave; nt < 8; nt += 4) {
    int cn = nt*16;
    short8 bfrag = ldcvt8(Wp + (size_t)(cn + lr)*32 + lq*8);
    float bias = bp[cn + lr];
    #pragma unroll
    for (int mt = 0; mt < 2; ++mt) {
      f32x4 c = MFMA16(ahk[mt], bfrag, z);
      #pragma unroll
      for (int r = 0; r < 4; ++r)
        hT[(mt*16 + lq*4 + r)*136 + cn + lr] = __float2bfloat16(c[r] + bias);
    }
  }
  __syncthreads();

  short8 ah[2][4];
  #pragma unroll
  for (int mt = 0; mt < 2; ++mt)
    #pragma unroll
    for (int kt = 0; kt < 4; ++kt)
      ah[mt][kt] = *reinterpret_cast<const short8*>(&hT[(mt*16 + lr)*136 + kt*32 + lq*8]);

  for (int nt = wave; nt < 24; nt += 4) {
    int which = nt >> 3;            // 0=q, 1=k, 2=v
    int c = (nt & 7)*16 + lr;
    const float* wrow = Win + (size_t)(which*128 + c)*128;
    float bias = binp[which*128 + c];
    f32x4 acc0 = z, acc1 = z;
    #pragma unroll
    for (int kt = 0; kt < 4; ++kt) {
      short8 bfrag = ldcvt8(wrow + kt*32 + lq*8);
      if (which == 0) {
        acc0 = MFMA16(alob[0][kt], bfrag, acc0);
        acc1 = MFMA16(alob[1][kt], bfrag, acc1);
      } else {
        acc0 = MFMA16(ah[0][kt], bfrag, acc0);
        acc1 = MFMA16(ah[1][kt], bfrag, acc1);
      }
    }
    int head = c >> 5, dd = c & 31;
    #pragma unroll
    for (int mt = 0; mt < 2; ++mt) {
      f32x4 acc = mt ? acc1 : acc0;
      #pragma unroll
      for (int r = 0; r < 4; ++r) {
        int row = mt*16 + lq*4 + r;
        float val = acc[r] + bias;
        if (which == 0)
          qg[((size_t)(b*HH + head)*TT + t0 + row)*32 + dd] = __float2bfloat16(val * SCALE);
        else if (which == 1)
          kg[((size_t)(b*HH + head)*TT + t0 + row)*32 + dd] = __float2bfloat16(val);
        else
          vT[c*40 + row] = __float2bfloat16(val);
      }
    }
  }
  __syncthreads();

  {
    int dd = tid >> 1, half = tid & 1;
    int bh = b*HH + (dd >> 5);
    short8 s0 = *reinterpret_cast<const short8*>(&vT[dd*40 + half*16]);
    short8 s1 = *reinterpret_cast<const short8*>(&vT[dd*40 + half*16 + 8]);
    bf16* dst = vtg + ((size_t)bh*32 + (dd & 31))*TT + t0 + half*16;
    *reinterpret_cast<short8*>(dst) = s0;
    *reinterpret_cast<short8*>(dst + 8) = s1;
  }
}

// ---------------- Kernel 2: softmax denominators l[b,h,t] -------------------
__global__ __launch_bounds__(64) void lsum_kernel(const bf16* __restrict__ qg,
    const bf16* __restrict__ kg, float* __restrict__ lg) {
  int bh = blockIdx.x >> 6, qt = blockIdx.x & 63;
  int lane = threadIdx.x;
  int lr = lane & 15, lq = lane >> 4;
  const bf16* qp = qg + ((size_t)(bh*TT) + qt*32)*32;
  short8 a0 = ldg8(qp + lr*32 + lq*8);
  short8 a1 = ldg8(qp + (16+lr)*32 + lq*8);
  float rs[2][4] = {{0.f,0.f,0.f,0.f},{0.f,0.f,0.f,0.f}};
  for (int kt = 0; kt < 64; ++kt) {
    const bf16* kp = kg + ((size_t)(bh*TT) + kt*32)*32;
    short8 b0 = ldg8(kp + lr*32 + lq*8);
    short8 b1 = ldg8(kp + (16+lr)*32 + lq*8);
    f32x4 z = {0.f,0.f,0.f,0.f};
    f32x4 s00 = MFMA16(a0, b0, z);
    f32x4 s01 = MFMA16(a0, b1, z);
    f32x4 s10 = MFMA16(a1, b0, z);
    f32x4 s11 = MFMA16(a1, b1, z);
    #pragma unroll
    for (int r = 0; r < 4; ++r) {
      rs[0][r] += __expf(s00[r]) + __expf(s01[r]);
      rs[1][r] += __expf(s10[r]) + __expf(s11[r]);
    }
  }
  #pragma unroll
  for (int m = 1; m <= 8; m <<= 1) {
    #pragma unroll
    for (int mt = 0; mt < 2; ++mt)
      #pragma unroll
      for (int r = 0; r < 4; ++r)
        rs[mt][r] += __shfl_xor(rs[mt][r], m, 64);
  }
  if (lr == 0) {
    #pragma unroll
    for (int mt = 0; mt < 2; ++mt)
      #pragma unroll
      for (int r = 0; r < 4; ++r)
        lg[(size_t)bh*TT + qt*32 + mt*16 + lq*4 + r] = rs[mt][r];
  }
}

// ---------------- Kernel 3: attention, S^T formulation ----------------------
// Block: 2 q-groups x 2 k-halves (4 waves). Each wave: 16 q-rows, ALL 4 heads,
// 1024-k half. S^T = K.Q^T -> C-layout col=q, row=k: head-mean in registers,
// f32x4 attn_w stores; P -> LDS (packed bf16) -> A-frag (b128) for PV.
__global__ __launch_bounds__(256, 2) void attn_kernel(const bf16* __restrict__ qg,
    const bf16* __restrict__ kg, const bf16* __restrict__ vtg,
    const float* __restrict__ lg, float* __restrict__ attn_out,
    float* __restrict__ ctxg) {
  __shared__ __align__(16) char smem[20608]; // pT 4w*4h*1280B = 20480 / pred 2*2112*4 = 16896 (union)
  bf16*  pT   = (bf16*)smem;
  float* pred = (float*)smem;
  int tid = threadIdx.x;
  int wave = tid >> 6, lane = tid & 63;
  int lr = lane & 15, lq = lane >> 4;
  int qg2 = wave & 1, kh = wave >> 1;
  int r0 = blockIdx.x * 32;
  int b  = r0 >> 11;
  int t0 = (r0 & 2047) + qg2*16;
  f32x4 z = {0.f,0.f,0.f,0.f};

  short8 qf[4];
  float  rinv[4];
  #pragma unroll
  for (int h = 0; h < 4; ++h) {
    size_t bhT = (size_t)(b*HH + h)*TT;
    qf[h]   = ldg8(qg + (bhT + t0 + lr)*32 + lq*8);
    rinv[h] = 1.0f / lg[bhT + t0 + lr];
  }
  f32x4 acc[4][2];
  #pragma unroll
  for (int h = 0; h < 4; ++h) { acc[h][0] = z; acc[h][1] = z; }

  for (int kt = 0; kt < 32; ++kt) {
    int kb = kh*1024 + kt*32;
    __syncthreads();   // keep same-k wave pairs in lockstep for L1 reuse
    f32x4 m0 = z, m1 = z;
    #pragma unroll
    for (int h = 0; h < 4; ++h) {
      size_t bhT = (size_t)(b*HH + h)*TT;
      const bf16* kp = kg + (bhT + kb + lr)*32 + lq*8;
      short8 kf0 = ldg8(kp);
      short8 kf1 = ldg8(kp + 16*32);
      const bf16* vp = vtg + ((size_t)(b*HH + h)*32 + lr)*TT + kb + lq*8;
      short8 vf0 = ldg8(vp);
      short8 vf1 = ldg8(vp + (size_t)16*TT);
      f32x4 tt0 = MFMA16(kf0, qf[h], z);   // S^T[kk=lq*4+r][q=lr], kk 0..15
      f32x4 tt1 = MFMA16(kf1, qf[h], z);   // kk 16..31
      f32x4 p0, p1;
      #pragma unroll
      for (int r = 0; r < 4; ++r) {
        p0[r] = __expf(tt0[r]) * rinv[h];
        p1[r] = __expf(tt1[r]) * rinv[h];
      }
      m0 += p0; m1 += p1;
      s16x4 w0, w1;
      #pragma unroll
      for (int r = 0; r < 4; ++r) { w0[r] = f2bs(p0[r]); w1[r] = f2bs(p1[r]); }
      bf16* pb = pT + wave*2560 + h*640 + lr*40;   // row q=lr, stride 40
      *reinterpret_cast<s16x4*>(pb + lq*4)      = w0;   // cols lq*4..+3
      *reinterpret_cast<s16x4*>(pb + 16 + lq*4) = w1;   // cols 16+lq*4..+3
      short8 ap = *reinterpret_cast<const short8*>(pb + lq*8);  // A[m=q][k=lq*8+j]
      acc[h][0] = MFMA16(ap, vf0, acc[h][0]);
      acc[h][1] = MFMA16(ap, vf1, acc[h][1]);
    }
    // head-mean straight from registers, coalesced f32x4
    float* dst = attn_out + ((size_t)(b*TT) + t0 + lr)*TT + kb + lq*4;
    f32x4 s0 = m0 * 0.25f, s1 = m1 * 0.25f;
    *reinterpret_cast<f32x4*>(dst)      = s0;
    *reinterpret_cast<f32x4*>(dst + 16) = s1;
  }

  // k-split ctx reduction: kh==1 waves dump partials, kh==0 adds and stores
  __syncthreads();
  if (kh == 1) {
    float* pr = pred + qg2*2112;
    #pragma unroll
    for (int h = 0; h < 4; ++h)
      #pragma unroll
      for (int nt = 0; nt < 2; ++nt)
        #pragma unroll
        for (int r = 0; r < 4; ++r)
          pr[(lq*4 + r)*132 + h*32 + nt*16 + lr] = acc[h][nt][r];
  }
  __syncthreads();
  if (kh == 0) {
    float* pr = pred + qg2*2112;
    #pragma unroll
    for (int h = 0; h < 4; ++h)
      #pragma unroll
      for (int nt = 0; nt < 2; ++nt)
        #pragma unroll
        for (int r = 0; r < 4; ++r) {
          float v = acc[h][nt][r] + pr[(lq*4 + r)*132 + h*32 + nt*16 + lr];
          ctxg[((size_t)(b*TT) + t0 + lq*4 + r)*128 + h*32 + nt*16 + lr] = v;
        }
  }
}

// ---------------- Kernel 4: out-proj + residual + LayerNorm -----------------
__global__ __launch_bounds__(256) void outln_kernel(const float* __restrict__ ctxg,
    const float* __restrict__ lob, const float* __restrict__ Wo,
    const float* __restrict__ bo, const float* __restrict__ gamma,
    const float* __restrict__ beta, float* __restrict__ outg) {
  __shared__ float sWo[128*129];
  __shared__ float sP[384];
  __shared__ float sCtx[4][128];
  __shared__ float sLob[4][128];
  int tid = threadIdx.x;
  for (int i = tid; i < 128*128; i += 256) {
    int c = i >> 7, d = i & 127;
    sWo[d*129 + c] = Wo[i];
  }
  if (tid < 128) {
    sP[tid] = bo[tid]; sP[128+tid] = gamma[tid]; sP[256+tid] = beta[tid];
  }
  __syncthreads();
  int wave = tid >> 6, lane = tid & 63;
  for (int it = 0; it < 8; ++it) {
    int row = blockIdx.x*32 + it*4 + wave;
    sCtx[wave][lane]    = ctxg[(size_t)row*128 + lane];
    sCtx[wave][64+lane] = ctxg[(size_t)row*128 + 64 + lane];
    sLob[wave][lane]    = lob[(size_t)row*128 + lane];
    sLob[wave][64+lane] = lob[(size_t)row*128 + 64 + lane];
    __syncthreads();
    float x0 = sP[lane] + sLob[wave][lane];
    float x1 = sP[64+lane] + sLob[wave][64+lane];
    #pragma unroll 8
    for (int d = 0; d < 128; ++d) {
      float cv = sCtx[wave][d];
      x0 += cv * sWo[d*129 + lane];
      x1 += cv * sWo[d*129 + 64 + lane];
    }
    float sum = x0 + x1;
    #pragma unroll
    for (int m = 1; m < 64; m <<= 1) sum += __shfl_xor(sum, m, 64);
    float mu = sum * (1.0f/128.0f);
    float d0 = x0 - mu, d1 = x1 - mu;
    float vs = d0*d0 + d1*d1;
    #pragma unroll
    for (int m = 1; m < 64; m <<= 1) vs += __shfl_xor(vs, m, 64);
    float rstd = rsqrtf(vs*(1.0f/128.0f) + 1e-5f);
    outg[(size_t)row*128 + lane]      = d0*rstd*sP[128+lane] + sP[256+lane];
    outg[(size_t)row*128 + 64 + lane] = d1*rstd*sP[192+lane] + sP[320+lane];
    __syncthreads();
  }
}

extern "C" void kernel_launch(void* const* d_in, const int* in_sizes, int n_in,
                              void* d_out, int out_size, void* d_ws, size_t ws_size,
                              hipStream_t stream) {
  const float* lob    = (const float*)d_in[0];
  const float* hawkes = (const float*)d_in[1];
  const float* Wp     = (const float*)d_in[2];
  const float* bp     = (const float*)d_in[3];
  const float* Win    = (const float*)d_in[4];
  const float* binp   = (const float*)d_in[5];
  const float* Wo     = (const float*)d_in[6];
  const float* bo     = (const float*)d_in[7];
  const float* gamma  = (const float*)d_in[8];
  const float* beta   = (const float*)d_in[9];
  float* outg = (float*)d_out;
  float* attn_out = outg + (size_t)BT*128;

  char* ws = (char*)d_ws;
  bf16*  qg   = (bf16*)(ws);
  bf16*  kg   = (bf16*)(ws + (size_t)4*1024*1024);
  bf16*  vtg  = (bf16*)(ws + (size_t)8*1024*1024);
  float* lg   = (float*)(ws + (size_t)12*1024*1024);
  float* ctxg = (float*)(ws + (size_t)12*1024*1024 + 512*1024);

  proj_kernel<<<BT/32, 256, 0, stream>>>(lob, hawkes, Wp, bp, Win, binp, qg, kg, vtg);
  lsum_kernel<<<BH*(TT/32), 64, 0, stream>>>(qg, kg, lg);
  attn_kernel<<<BT/32, 256, 0, stream>>>(qg, kg, vtg, lg, attn_out, ctxg);
  outln_kernel<<<512, 256, 0, stream>>>(ctxg, lob, Wo, bo, gamma, beta, outg);
}

// Round 7
// 320.849 us; speedup vs baseline: 1.0356x; 1.0356x over previous
//
#include <hip/hip_runtime.h>
#include <hip/hip_bf16.h>

#define TT 2048
#define BB 8
#define DD 128
#define HH 4
#define BT (BB*TT)
#define SCALE 0.1767766952966369f

typedef __attribute__((ext_vector_type(8))) short short8;
typedef __attribute__((ext_vector_type(4))) short s16x4;
typedef __attribute__((ext_vector_type(4))) float f32x4;
typedef __hip_bfloat16 bf16;

#define MFMA16(a,b,c) __builtin_amdgcn_mfma_f32_16x16x32_bf16(a,b,c,0,0,0)

static __device__ inline short8 ldg8(const bf16* p) {
  return *reinterpret_cast<const short8*>(p);
}
static __device__ inline float b2f(bf16 x) { return __bfloat162float(x); }
static __device__ inline short f2bs(float x) {
  bf16 h = __float2bfloat16(x);
  return *reinterpret_cast<short*>(&h);
}
static __device__ inline short8 ldcvt8(const float* p) {
  f32x4 f0 = *reinterpret_cast<const f32x4*>(p);
  f32x4 f1 = *reinterpret_cast<const f32x4*>(p + 4);
  short8 r;
  #pragma unroll
  for (int i = 0; i < 4; ++i) { r[i] = f2bs(f0[i]); r[4+i] = f2bs(f1[i]); }
  return r;
}

// ---------------- Kernel 1: MFMA projections (unchanged) ----------------
__global__ __launch_bounds__(256) void proj_kernel(
    const float* __restrict__ lob, const float* __restrict__ hawkes,
    const float* __restrict__ Wp, const float* __restrict__ bp,
    const float* __restrict__ Win, const float* __restrict__ binp,
    bf16* __restrict__ qg, bf16* __restrict__ kg, bf16* __restrict__ vtg) {
  __shared__ bf16 hT[32*136];
  __shared__ bf16 vT[128*40];
  int tid = threadIdx.x;
  int wave = tid >> 6, lane = tid & 63;
  int lr = lane & 15, lq = lane >> 4;
  int r0 = blockIdx.x * 32;
  int b  = r0 >> 11, t0 = r0 & 2047;
  f32x4 z = {0.f,0.f,0.f,0.f};

  short8 alob[2][4], ahk[2];
  #pragma unroll
  for (int mt = 0; mt < 2; ++mt) {
    const float* lp = lob + (size_t)(r0 + mt*16 + lr)*128;
    #pragma unroll
    for (int kt = 0; kt < 4; ++kt) alob[mt][kt] = ldcvt8(lp + kt*32 + lq*8);
    ahk[mt] = ldcvt8(hawkes + (size_t)(r0 + mt*16 + lr)*32 + lq*8);
  }

  for (int nt = wave; nt < 8; nt += 4) {
    int cn = nt*16;
    short8 bfrag = ldcvt8(Wp + (size_t)(cn + lr)*32 + lq*8);
    float bias = bp[cn + lr];
    #pragma unroll
    for (int mt = 0; mt < 2; ++mt) {
      f32x4 c = MFMA16(ahk[mt], bfrag, z);
      #pragma unroll
      for (int r = 0; r < 4; ++r)
        hT[(mt*16 + lq*4 + r)*136 + cn + lr] = __float2bfloat16(c[r] + bias);
    }
  }
  __syncthreads();

  short8 ah[2][4];
  #pragma unroll
  for (int mt = 0; mt < 2; ++mt)
    #pragma unroll
    for (int kt = 0; kt < 4; ++kt)
      ah[mt][kt] = *reinterpret_cast<const short8*>(&hT[(mt*16 + lr)*136 + kt*32 + lq*8]);

  for (int nt = wave; nt < 24; nt += 4) {
    int which = nt >> 3;
    int c = (nt & 7)*16 + lr;
    const float* wrow = Win + (size_t)(which*128 + c)*128;
    float bias = binp[which*128 + c];
    f32x4 acc0 = z, acc1 = z;
    #pragma unroll
    for (int kt = 0; kt < 4; ++kt) {
      short8 bfrag = ldcvt8(wrow + kt*32 + lq*8);
      if (which == 0) {
        acc0 = MFMA16(alob[0][kt], bfrag, acc0);
        acc1 = MFMA16(alob[1][kt], bfrag, acc1);
      } else {
        acc0 = MFMA16(ah[0][kt], bfrag, acc0);
        acc1 = MFMA16(ah[1][kt], bfrag, acc1);
      }
    }
    int head = c >> 5, dd = c & 31;
    #pragma unroll
    for (int mt = 0; mt < 2; ++mt) {
      f32x4 acc = mt ? acc1 : acc0;
      #pragma unroll
      for (int r = 0; r < 4; ++r) {
        int row = mt*16 + lq*4 + r;
        float val = acc[r] + bias;
        if (which == 0)
          qg[((size_t)(b*HH + head)*TT + t0 + row)*32 + dd] = __float2bfloat16(val * SCALE);
        else if (which == 1)
          kg[((size_t)(b*HH + head)*TT + t0 + row)*32 + dd] = __float2bfloat16(val);
        else
          vT[c*40 + row] = __float2bfloat16(val);
      }
    }
  }
  __syncthreads();

  {
    int dd = tid >> 1, half = tid & 1;
    int bh = b*HH + (dd >> 5);
    short8 s0 = *reinterpret_cast<const short8*>(&vT[dd*40 + half*16]);
    short8 s1 = *reinterpret_cast<const short8*>(&vT[dd*40 + half*16 + 8]);
    bf16* dst = vtg + ((size_t)bh*32 + (dd & 31))*TT + t0 + half*16;
    *reinterpret_cast<short8*>(dst) = s0;
    *reinterpret_cast<short8*>(dst + 8) = s1;
  }
}

// ---------------- Kernel 2: fused attention (denominators + attn_w + PV) ----
// Block = 16 q-rows, 4 waves = 4 k-quarters (512 keys each), all 4 heads/wave.
// Phase 1: per-wave partial softmax denominators, cross-wave LDS reduce.
// Phase 2: no barriers; wave-private double-buffered P tiles; PV(kt-1) reads
// the buffer written a full iteration earlier (LDS latency hidden).
__global__ __launch_bounds__(256, 3) void attn_kernel(const bf16* __restrict__ qg,
    const bf16* __restrict__ kg, const bf16* __restrict__ vtg,
    float* __restrict__ attn_out, float* __restrict__ ctxg) {
  __shared__ __align__(16) char smem[41984];
  bf16*  pT   = (bf16*)smem;                     // [4 wave][2 buf][4 h][16*40]
  float* slw  = (float*)(smem + 40960);          // [4h][16q][4w]
  float* pred = (float*)smem;                    // alias (ctx reduce)
  int tid = threadIdx.x;
  int wave = tid >> 6, lane = tid & 63;
  int lr = lane & 15, lq = lane >> 4;
  int row0 = blockIdx.x * 16;
  int b  = row0 >> 11, t0 = row0 & 2047;
  f32x4 z = {0.f,0.f,0.f,0.f};

  short8 qf[4];
  #pragma unroll
  for (int h = 0; h < 4; ++h)
    qf[h] = ldg8(qg + ((size_t)(b*HH + h)*TT + t0 + lr)*32 + lq*8);

  // ---- phase 1: denominators ----
  float ls[4] = {0.f,0.f,0.f,0.f};
  for (int kt = 0; kt < 16; ++kt) {
    int kb = wave*512 + kt*32;
    #pragma unroll
    for (int h = 0; h < 4; ++h) {
      const bf16* kp = kg + ((size_t)(b*HH + h)*TT + kb + lr)*32 + lq*8;
      short8 kf0 = ldg8(kp);
      short8 kf1 = ldg8(kp + 16*32);
      f32x4 tt0 = MFMA16(kf0, qf[h], z);
      f32x4 tt1 = MFMA16(kf1, qf[h], z);
      #pragma unroll
      for (int r = 0; r < 4; ++r) ls[h] += __expf(tt0[r]) + __expf(tt1[r]);
    }
  }
  #pragma unroll
  for (int h = 0; h < 4; ++h) {
    ls[h] += __shfl_xor(ls[h], 16, 64);
    ls[h] += __shfl_xor(ls[h], 32, 64);
  }
  if (lane < 16) {
    #pragma unroll
    for (int h = 0; h < 4; ++h) slw[(h*16 + lane)*4 + wave] = ls[h];
  }
  __syncthreads();
  float rinv[4];
  #pragma unroll
  for (int h = 0; h < 4; ++h) {
    f32x4 v = *reinterpret_cast<const f32x4*>(&slw[(h*16 + lr)*4]);
    rinv[h] = 1.0f / (v[0] + v[1] + v[2] + v[3]);
  }

  // ---- phase 2: attn_w + PV, software-pipelined ----
  f32x4 acc[4][2];
  #pragma unroll
  for (int h = 0; h < 4; ++h) { acc[h][0] = z; acc[h][1] = z; }
  bf16* myP = pT + wave*5120;

  auto computeP = [&](int kt) {
    int kb = wave*512 + kt*32;
    f32x4 m0 = z, m1 = z;
    bf16* buf = myP + (kt & 1)*2560;
    #pragma unroll
    for (int h = 0; h < 4; ++h) {
      const bf16* kp = kg + ((size_t)(b*HH + h)*TT + kb + lr)*32 + lq*8;
      short8 kf0 = ldg8(kp);
      short8 kf1 = ldg8(kp + 16*32);
      f32x4 tt0 = MFMA16(kf0, qf[h], z);   // S^T[kk=lq*4+r][q=lr]
      f32x4 tt1 = MFMA16(kf1, qf[h], z);   // kk 16..31
      f32x4 p0, p1;
      #pragma unroll
      for (int r = 0; r < 4; ++r) {
        p0[r] = __expf(tt0[r]) * rinv[h];
        p1[r] = __expf(tt1[r]) * rinv[h];
      }
      m0 += p0; m1 += p1;
      s16x4 w0, w1;
      #pragma unroll
      for (int r = 0; r < 4; ++r) { w0[r] = f2bs(p0[r]); w1[r] = f2bs(p1[r]); }
      bf16* pb = buf + h*640 + lr*40;      // row q=lr, 32 cols, stride 40
      *reinterpret_cast<s16x4*>(pb + lq*4)      = w0;
      *reinterpret_cast<s16x4*>(pb + 16 + lq*4) = w1;
    }
    float* dst = attn_out + ((size_t)(b*TT) + t0 + lr)*TT + kb + lq*4;
    f32x4 s0 = m0 * 0.25f, s1 = m1 * 0.25f;
    *reinterpret_cast<f32x4*>(dst)      = s0;
    *reinterpret_cast<f32x4*>(dst + 16) = s1;
  };
  auto doPV = [&](int kt) {
    int kb = wave*512 + kt*32;
    bf16* buf = myP + (kt & 1)*2560;
    #pragma unroll
    for (int h = 0; h < 4; ++h) {
      const bf16* vp = vtg + ((size_t)(b*HH + h)*32 + lr)*TT + kb + lq*8;
      short8 vf0 = ldg8(vp);
      short8 vf1 = ldg8(vp + (size_t)16*TT);
      short8 ap = *reinterpret_cast<const short8*>(buf + h*640 + lr*40 + lq*8);
      acc[h][0] = MFMA16(ap, vf0, acc[h][0]);
      acc[h][1] = MFMA16(ap, vf1, acc[h][1]);
    }
  };

  computeP(0);
  for (int kt = 1; kt < 16; ++kt) {
    doPV(kt - 1);
    computeP(kt);
  }
  doPV(15);

  // ---- cross-wave ctx reduction ----
  __syncthreads();   // pT dead; pred aliases it
  #pragma unroll
  for (int h = 0; h < 4; ++h)
    #pragma unroll
    for (int nt = 0; nt < 2; ++nt)
      #pragma unroll
      for (int r = 0; r < 4; ++r)
        pred[wave*2112 + (lq*4 + r)*132 + h*32 + nt*16 + lr] = acc[h][nt][r];
  __syncthreads();
  {
    int q = tid >> 4, d0 = (tid & 15)*8;
    f32x4 s0 = z, s1 = z;
    #pragma unroll
    for (int w = 0; w < 4; ++w) {
      s0 += *reinterpret_cast<const f32x4*>(&pred[w*2112 + q*132 + d0]);
      s1 += *reinterpret_cast<const f32x4*>(&pred[w*2112 + q*132 + d0 + 4]);
    }
    float* cdst = ctxg + ((size_t)(b*TT) + t0 + q)*128 + d0;
    *reinterpret_cast<f32x4*>(cdst)     = s0;
    *reinterpret_cast<f32x4*>(cdst + 4) = s1;
  }
}

// ---------------- Kernel 3: out-proj + residual + LayerNorm (unchanged) -----
__global__ __launch_bounds__(256) void outln_kernel(const float* __restrict__ ctxg,
    const float* __restrict__ lob, const float* __restrict__ Wo,
    const float* __restrict__ bo, const float* __restrict__ gamma,
    const float* __restrict__ beta, float* __restrict__ outg) {
  __shared__ float sWo[128*129];
  __shared__ float sP[384];
  __shared__ float sCtx[4][128];
  __shared__ float sLob[4][128];
  int tid = threadIdx.x;
  for (int i = tid; i < 128*128; i += 256) {
    int c = i >> 7, d = i & 127;
    sWo[d*129 + c] = Wo[i];
  }
  if (tid < 128) {
    sP[tid] = bo[tid]; sP[128+tid] = gamma[tid]; sP[256+tid] = beta[tid];
  }
  __syncthreads();
  int wave = tid >> 6, lane = tid & 63;
  for (int it = 0; it < 8; ++it) {
    int row = blockIdx.x*32 + it*4 + wave;
    sCtx[wave][lane]    = ctxg[(size_t)row*128 + lane];
    sCtx[wave][64+lane] = ctxg[(size_t)row*128 + 64 + lane];
    sLob[wave][lane]    = lob[(size_t)row*128 + lane];
    sLob[wave][64+lane] = lob[(size_t)row*128 + 64 + lane];
    __syncthreads();
    float x0 = sP[lane] + sLob[wave][lane];
    float x1 = sP[64+lane] + sLob[wave][64+lane];
    #pragma unroll 8
    for (int d = 0; d < 128; ++d) {
      float cv = sCtx[wave][d];
      x0 += cv * sWo[d*129 + lane];
      x1 += cv * sWo[d*129 + 64 + lane];
    }
    float sum = x0 + x1;
    #pragma unroll
    for (int m = 1; m < 64; m <<= 1) sum += __shfl_xor(sum, m, 64);
    float mu = sum * (1.0f/128.0f);
    float d0 = x0 - mu, d1 = x1 - mu;
    float vs = d0*d0 + d1*d1;
    #pragma unroll
    for (int m = 1; m < 64; m <<= 1) vs += __shfl_xor(vs, m, 64);
    float rstd = rsqrtf(vs*(1.0f/128.0f) + 1e-5f);
    outg[(size_t)row*128 + lane]      = d0*rstd*sP[128+lane] + sP[256+lane];
    outg[(size_t)row*128 + 64 + lane] = d1*rstd*sP[192+lane] + sP[320+lane];
    __syncthreads();
  }
}

extern "C" void kernel_launch(void* const* d_in, const int* in_sizes, int n_in,
                              void* d_out, int out_size, void* d_ws, size_t ws_size,
                              hipStream_t stream) {
  const float* lob    = (const float*)d_in[0];
  const float* hawkes = (const float*)d_in[1];
  const float* Wp     = (const float*)d_in[2];
  const float* bp     = (const float*)d_in[3];
  const float* Win    = (const float*)d_in[4];
  const float* binp   = (const float*)d_in[5];
  const float* Wo     = (const float*)d_in[6];
  const float* bo     = (const float*)d_in[7];
  const float* gamma  = (const float*)d_in[8];
  const float* beta   = (const float*)d_in[9];
  float* outg = (float*)d_out;
  float* attn_out = outg + (size_t)BT*128;

  char* ws = (char*)d_ws;
  bf16*  qg   = (bf16*)(ws);
  bf16*  kg   = (bf16*)(ws + (size_t)4*1024*1024);
  bf16*  vtg  = (bf16*)(ws + (size_t)8*1024*1024);
  float* ctxg = (float*)(ws + (size_t)12*1024*1024 + 512*1024);

  proj_kernel<<<BT/32, 256, 0, stream>>>(lob, hawkes, Wp, bp, Win, binp, qg, kg, vtg);
  attn_kernel<<<BT/16, 256, 0, stream>>>(qg, kg, vtg, attn_out, ctxg);
  outln_kernel<<<512, 256, 0, stream>>>(ctxg, lob, Wo, bo, gamma, beta, outg);
}